// Round 1
// baseline (61.212 us; speedup 1.0000x reference)
//
#include <hip/hip_runtime.h>
#include <hip/hip_bf16.h>

// out[8192,64] = L[8192,8192] (fp32) @ M[8192,64] (fp32)
// bf16 MFMA path, split-K=8 with fp32 atomics, reg-staged LDS tiles.

#define NPED 8192
#define HID  64
#define BM   64
#define BK   64
#define KSPLIT 8
#define KRANGE (NPED / KSPLIT)   // 1024
#define NSTEPS (KRANGE / BK)     // 16

typedef __bf16 bf16x8 __attribute__((ext_vector_type(8)));
typedef float  f32x4  __attribute__((ext_vector_type(4)));
using u16 = unsigned short;

struct alignas(8) US4 { u16 x, y, z, w; };

// fp32 -> bf16 round-to-nearest-even
__device__ __forceinline__ u16 f2bf(float f) {
    unsigned u = __builtin_bit_cast(unsigned, f);
    unsigned r = (u + 0x7fffu + ((u >> 16) & 1u)) >> 16;
    return (u16)r;
}

// swizzled LDS byte offset for [row][kbyte] tile, 128 B per row
__device__ __forceinline__ int swz(int row, int kbyte) {
    return (row << 7) + (kbyte ^ ((row & 7) << 4));
}

__global__ __launch_bounds__(256, 4)
void crowd_mm(const float* __restrict__ A, const float* __restrict__ B,
              float* __restrict__ out) {
    __shared__ u16 As[BM * BK];   // [row][k], swizzled, 8 KB
    __shared__ u16 Bs[HID * BK];  // [h][k] (transposed), swizzled, 8 KB

    const int tid  = threadIdx.x;
    const int lane = tid & 63;
    const int w    = tid >> 6;        // wave id 0..3
    const int rb   = blockIdx.x;      // row block
    const int ks   = blockIdx.y;      // k-split slice
    const int k_base = ks * KRANGE;

    // A staging: idx = it*256+tid -> row = idx>>4 (16 rows per it), c4 = idx&15
    const int a_row = tid >> 4;       // 0..15 (+ it*16)
    const int a_c4  = tid & 15;
    // B staging: h = lane, kq = it*4 + w
    const int b_h   = tid & 63;

    const float* Agp = A + (long)(rb * BM) * NPED + k_base;
    const float* Bgp = B + (long)k_base * HID;

    float4 a_reg[4];
    float  b_reg[4][4];

    auto load_tile = [&](int step) {
        const int kk = step * BK;
        #pragma unroll
        for (int it = 0; it < 4; ++it) {
            int row = a_row + it * 16;
            a_reg[it] = *reinterpret_cast<const float4*>(
                Agp + (long)row * NPED + kk + a_c4 * 4);
        }
        #pragma unroll
        for (int it = 0; it < 4; ++it) {
            int kq = it * 4 + w;
            #pragma unroll
            for (int j = 0; j < 4; ++j) {
                b_reg[it][j] = Bgp[(kk + kq * 4 + j) * HID + b_h];
            }
        }
    };

    auto store_tile = [&]() {
        char* Ab = reinterpret_cast<char*>(As);
        char* Bb = reinterpret_cast<char*>(Bs);
        #pragma unroll
        for (int it = 0; it < 4; ++it) {
            int row = a_row + it * 16;
            US4 v;
            v.x = f2bf(a_reg[it].x); v.y = f2bf(a_reg[it].y);
            v.z = f2bf(a_reg[it].z); v.w = f2bf(a_reg[it].w);
            *reinterpret_cast<US4*>(Ab + swz(row, a_c4 * 8)) = v;
        }
        #pragma unroll
        for (int it = 0; it < 4; ++it) {
            int kq = it * 4 + w;
            US4 v;
            v.x = f2bf(b_reg[it][0]); v.y = f2bf(b_reg[it][1]);
            v.z = f2bf(b_reg[it][2]); v.w = f2bf(b_reg[it][3]);
            *reinterpret_cast<US4*>(Bb + swz(b_h, kq * 8)) = v;
        }
    };

    f32x4 acc[4] = {f32x4{0.f,0.f,0.f,0.f}, f32x4{0.f,0.f,0.f,0.f},
                    f32x4{0.f,0.f,0.f,0.f}, f32x4{0.f,0.f,0.f,0.f}};

    auto do_mfma = [&]() {
        const char* Ab = reinterpret_cast<const char*>(As);
        const char* Bb = reinterpret_cast<const char*>(Bs);
        #pragma unroll
        for (int s = 0; s < 2; ++s) {
            const int arow  = w * 16 + (lane & 15);
            const int kbyte = s * 64 + (lane >> 4) * 16;
            bf16x8 afrag = *reinterpret_cast<const bf16x8*>(Ab + swz(arow, kbyte));
            #pragma unroll
            for (int t = 0; t < 4; ++t) {
                const int brow = t * 16 + (lane & 15);
                bf16x8 bfrag = *reinterpret_cast<const bf16x8*>(Bb + swz(brow, kbyte));
                acc[t] = __builtin_amdgcn_mfma_f32_16x16x32_bf16(afrag, bfrag, acc[t], 0, 0, 0);
            }
        }
    };

    load_tile(0);
    for (int step = 0; step < NSTEPS; ++step) {
        store_tile();
        __syncthreads();
        if (step + 1 < NSTEPS) load_tile(step + 1);  // overlap with MFMA phase
        do_mfma();
        __syncthreads();
    }

    // Epilogue: C/D layout col = lane&15, row = (lane>>4)*4 + reg (m89-verified)
    #pragma unroll
    for (int t = 0; t < 4; ++t) {
        #pragma unroll
        for (int r = 0; r < 4; ++r) {
            int row = rb * BM + w * 16 + (lane >> 4) * 4 + r;
            int col = t * 16 + (lane & 15);
            atomicAdd(&out[row * HID + col], acc[t][r]);
        }
    }
}

extern "C" void kernel_launch(void* const* d_in, const int* in_sizes, int n_in,
                              void* d_out, int out_size, void* d_ws, size_t ws_size,
                              hipStream_t stream) {
    const float* A = (const float*)d_in[0];   // location_data [8192, 8192]
    const float* B = (const float*)d_in[1];   // motion_data   [8192, 64]
    float* out = (float*)d_out;               // [8192, 64]

    hipMemsetAsync(d_out, 0, (size_t)out_size * sizeof(float), stream);

    dim3 grid(NPED / BM, KSPLIT);
    crowd_mm<<<grid, 256, 0, stream>>>(A, B, out);
}